// Round 1
// baseline (223.972 us; speedup 1.0000x reference)
//
#include <hip/hip_runtime.h>

// DCNv2-ish deformable conv, fp32.
// Pipeline: (1) x NCHW->NHWC transpose, (2) w_deform -> [kk][cin][cout],
// (3) 3x3 offset conv (18 ch), (4) bilinear sample + 64x576 contraction (GEMM).
// ws layout (floats): xT[4*64*16384] | offs[4*18*16384] | wdT[9*64*64]  (~21.7 MB)

#define BATCH 4
#define CIN   64
#define COUT  64
#define HH    128
#define WW    128
#define HWPIX (HH*WW)

__global__ __launch_bounds__(256) void transpose_x_kernel(const float* __restrict__ x,
                                                          float* __restrict__ xT) {
  __shared__ float tile[32][33];
  int b  = blockIdx.z;
  int p0 = blockIdx.x * 32;   // pixel tile (inner dim of NCHW)
  int c0 = blockIdx.y * 32;   // channel tile
  const float* xb = x + (size_t)b * CIN * HWPIX;
  float* xTb = xT + (size_t)b * HWPIX * CIN;
#pragma unroll
  for (int i = 0; i < 4; i++)
    tile[threadIdx.y + i * 8][threadIdx.x] =
        xb[(size_t)(c0 + threadIdx.y + i * 8) * HWPIX + p0 + threadIdx.x];
  __syncthreads();
#pragma unroll
  for (int i = 0; i < 4; i++)
    xTb[(size_t)(p0 + threadIdx.y + i * 8) * CIN + c0 + threadIdx.x] =
        tile[threadIdx.x][threadIdx.y + i * 8];
}

__global__ __launch_bounds__(256) void transpose_wd_kernel(const float* __restrict__ wd,
                                                           float* __restrict__ wdT) {
  int t = blockIdx.x * 256 + threadIdx.x;
  if (t >= 9 * 64 * 64) return;
  int cout = t & 63;
  int cin  = (t >> 6) & 63;
  int kk   = t >> 12;
  // wdT[kk][cin][cout] = wd[cout][cin][kk]
  wdT[t] = wd[cout * 576 + cin * 9 + kk];
}

__global__ __launch_bounds__(256) void offset_conv_kernel(const float* __restrict__ x,
                                                          const float* __restrict__ wo,
                                                          float* __restrict__ offs) {
  // wl[cin*9 + ki*3 + kj][c18], row pitch 20 floats (80B -> 16B aligned rows)
  __shared__ float wl[576][20];
  int tid = threadIdx.x;
  for (int i = tid; i < 18 * 576; i += 256) {
    int c = i % 18;
    int j = i / 18;
    wl[j][c] = wo[c * 576 + j];
  }
  __syncthreads();

  int gid = blockIdx.x * 256 + tid;           // 0..65535, one pixel each
  int b   = gid >> 14;
  int rem = gid & (HWPIX - 1);
  int y   = rem >> 7;
  int xx  = rem & 127;
  const float* xb = x + (size_t)b * CIN * HWPIX;

  float acc[18];
#pragma unroll
  for (int c = 0; c < 18; c++) acc[c] = 0.f;

  for (int cin = 0; cin < CIN; cin++) {
    const float* xc = xb + (size_t)cin * HWPIX;
#pragma unroll
    for (int ki = 0; ki < 3; ki++) {
      int yy = y + ki - 1;
      float r0 = 0.f, r1 = 0.f, r2 = 0.f;
      if (yy >= 0 && yy < HH) {
        const float* xr = xc + yy * WW;
        r0 = (xx > 0)      ? xr[xx - 1] : 0.f;
        r1 = xr[xx];
        r2 = (xx < WW - 1) ? xr[xx + 1] : 0.f;
      }
      const float* w0 = &wl[cin * 9 + ki * 3 + 0][0];
      const float* w1 = &wl[cin * 9 + ki * 3 + 1][0];
      const float* w2 = &wl[cin * 9 + ki * 3 + 2][0];
#pragma unroll
      for (int c = 0; c < 18; c++)
        acc[c] += r0 * w0[c] + r1 * w1[c] + r2 * w2[c];
    }
  }
  // offs[b][c18][y][x]; c18 = 2*kk + {0:dy, 1:dx} (conv channel order)
  float* ob = offs + (size_t)b * 18 * HWPIX + y * WW + xx;
#pragma unroll
  for (int c = 0; c < 18; c++) ob[(size_t)c * HWPIX] = acc[c];
}

__global__ __launch_bounds__(256) void deform_gemm_kernel(const float* __restrict__ xT,
                                                          const float* __restrict__ offs,
                                                          const float* __restrict__ wdT,
                                                          float* __restrict__ out) {
  __shared__ float samp[CIN][68];    // [cin][px], pitch 68 keeps b128 align, cheap conflicts
  __shared__ float wdl[CIN][COUT];   // wd chunk for current kk
  int tid = threadIdx.x;
  int bid = blockIdx.x;              // 1024 blocks: 4 b * 128 y * 2 half-rows
  int b   = bid >> 8;
  int r   = bid & 255;
  int y   = r >> 1;
  int x0  = (r & 1) << 6;            // 0 or 64

  // phase-1 mapping: 64 px * 4 cin-quarters
  int p1 = tid >> 2;
  int si = tid & 3;
  // phase-2 mapping: 16 cout-quads * 16 px-quads
  int ci = tid & 15;
  int pi = tid >> 4;

  const float* xTb = xT + (size_t)b * HWPIX * CIN;
  const float* ob  = offs + (size_t)b * 18 * HWPIX;

  float acc[4][4];
#pragma unroll
  for (int i = 0; i < 4; i++)
#pragma unroll
    for (int j = 0; j < 4; j++) acc[i][j] = 0.f;

  int xp = x0 + p1;
  int pixoff = y * WW + xp;

  for (int kk = 0; kk < 9; kk++) {
    // stage wd chunk [64 cin][64 cout], contiguous copy
    {
      const float4* src = (const float4*)(wdT + (size_t)kk * CIN * COUT);
      float4* dst = (float4*)&wdl[0][0];
#pragma unroll
      for (int i = 0; i < 4; i++) dst[tid + i * 256] = src[tid + i * 256];
    }
    // bilinear sample this kk for 64 px * 16 cin per thread
    {
      float dy = ob[(size_t)(2 * kk) * HWPIX + pixoff];
      float dx = ob[(size_t)(2 * kk + 1) * HWPIX + pixoff];
      float ys = (float)(y - 1 + kk / 3) + dy;
      float xs = (float)(xp - 1 + kk % 3) + dx;
      float y0f = floorf(ys), x0f = floorf(xs);
      float wy = ys - y0f, wx = xs - x0f;
      int iy0 = (int)y0f, ix0 = (int)x0f;
      int iy1 = iy0 + 1, ix1 = ix0 + 1;
      float w00 = (1.f - wy) * (1.f - wx), w01 = (1.f - wy) * wx;
      float w10 = wy * (1.f - wx), w11 = wy * wx;
      bool vy0 = (iy0 >= 0) && (iy0 < HH), vy1 = (iy1 >= 0) && (iy1 < HH);
      bool vx0 = (ix0 >= 0) && (ix0 < WW), vx1 = (ix1 >= 0) && (ix1 < WW);
      if (!(vy0 && vx0)) w00 = 0.f;
      if (!(vy0 && vx1)) w01 = 0.f;
      if (!(vy1 && vx0)) w10 = 0.f;
      if (!(vy1 && vx1)) w11 = 0.f;
      int cy0 = min(max(iy0, 0), HH - 1), cy1 = min(max(iy1, 0), HH - 1);
      int cx0 = min(max(ix0, 0), WW - 1), cx1 = min(max(ix1, 0), WW - 1);
      const float* q00 = xTb + ((size_t)(cy0 * WW + cx0)) * CIN + si * 16;
      const float* q01 = xTb + ((size_t)(cy0 * WW + cx1)) * CIN + si * 16;
      const float* q10 = xTb + ((size_t)(cy1 * WW + cx0)) * CIN + si * 16;
      const float* q11 = xTb + ((size_t)(cy1 * WW + cx1)) * CIN + si * 16;
#pragma unroll
      for (int c4 = 0; c4 < 4; c4++) {
        float4 v00 = *(const float4*)(q00 + c4 * 4);
        float4 v01 = *(const float4*)(q01 + c4 * 4);
        float4 v10 = *(const float4*)(q10 + c4 * 4);
        float4 v11 = *(const float4*)(q11 + c4 * 4);
        int cin = si * 16 + c4 * 4;
        samp[cin + 0][p1] = w00 * v00.x + w01 * v01.x + w10 * v10.x + w11 * v11.x;
        samp[cin + 1][p1] = w00 * v00.y + w01 * v01.y + w10 * v10.y + w11 * v11.y;
        samp[cin + 2][p1] = w00 * v00.z + w01 * v01.z + w10 * v10.z + w11 * v11.z;
        samp[cin + 3][p1] = w00 * v00.w + w01 * v01.w + w10 * v10.w + w11 * v11.w;
      }
    }
    __syncthreads();
    // GEMM chunk: acc[4 cout][4 px] += wdl[c][ci*4..] (x) samp[c][pi*4..]
#pragma unroll 16
    for (int c = 0; c < CIN; c++) {
      float4 wv = *(const float4*)&wdl[c][ci * 4];
      float4 sv = *(const float4*)&samp[c][pi * 4];
      acc[0][0] += wv.x * sv.x; acc[0][1] += wv.x * sv.y; acc[0][2] += wv.x * sv.z; acc[0][3] += wv.x * sv.w;
      acc[1][0] += wv.y * sv.x; acc[1][1] += wv.y * sv.y; acc[1][2] += wv.y * sv.z; acc[1][3] += wv.y * sv.w;
      acc[2][0] += wv.z * sv.x; acc[2][1] += wv.z * sv.y; acc[2][2] += wv.z * sv.z; acc[2][3] += wv.z * sv.w;
      acc[3][0] += wv.w * sv.x; acc[3][1] += wv.w * sv.y; acc[3][2] += wv.w * sv.z; acc[3][3] += wv.w * sv.w;
    }
    __syncthreads();
  }

  float* outb = out + (size_t)b * COUT * HWPIX + y * WW + x0 + pi * 4;
#pragma unroll
  for (int i = 0; i < 4; i++) {
    float4 v = make_float4(acc[i][0], acc[i][1], acc[i][2], acc[i][3]);
    *(float4*)(outb + (size_t)(ci * 4 + i) * HWPIX) = v;
  }
}

extern "C" void kernel_launch(void* const* d_in, const int* in_sizes, int n_in,
                              void* d_out, int out_size, void* d_ws, size_t ws_size,
                              hipStream_t stream) {
  const float* x  = (const float*)d_in[0];
  const float* wo = (const float*)d_in[1];
  const float* wd = (const float*)d_in[2];
  float* out = (float*)d_out;

  float* xT   = (float*)d_ws;
  float* offs = xT + (size_t)BATCH * CIN * HWPIX;
  float* wdT  = offs + (size_t)BATCH * 18 * HWPIX;

  transpose_x_kernel<<<dim3(HWPIX / 32, CIN / 32, BATCH), dim3(32, 8, 1), 0, stream>>>(x, xT);
  transpose_wd_kernel<<<dim3((9 * 64 * 64 + 255) / 256), dim3(256), 0, stream>>>(wd, wdT);
  offset_conv_kernel<<<dim3(BATCH * HWPIX / 256), dim3(256), 0, stream>>>(x, wo, offs);
  deform_gemm_kernel<<<dim3(BATCH * HWPIX / 64), dim3(256), 0, stream>>>(xT, offs, wdT, out);
}

// Round 2
// 215.433 us; speedup vs baseline: 1.0396x; 1.0396x over previous
//
#include <hip/hip_runtime.h>

// DCNv2-ish deformable conv, fp32.
// (1) x NCHW->NHWC transpose, (2) w_deform -> [kk][cin][cout],
// (3) 3x3 offset conv (18 ch, 2px/thread, float4 LDS weight reads),
// (4) bilinear sample + 64x576 GEMM with XCD-swizzled blocks.
// ws (floats): xT[4*64*16384] | offs[4*18*16384] | wdT[9*64*64]

#define BATCH 4
#define CIN   64
#define COUT  64
#define HH    128
#define WW    128
#define HWPIX (HH*WW)

__global__ __launch_bounds__(256) void transpose_x_kernel(const float* __restrict__ x,
                                                          float* __restrict__ xT) {
  __shared__ float tile[32][33];
  int b  = blockIdx.z;
  int p0 = blockIdx.x * 32;
  int c0 = blockIdx.y * 32;
  const float* xb = x + (size_t)b * CIN * HWPIX;
  float* xTb = xT + (size_t)b * HWPIX * CIN;
#pragma unroll
  for (int i = 0; i < 4; i++)
    tile[threadIdx.y + i * 8][threadIdx.x] =
        xb[(size_t)(c0 + threadIdx.y + i * 8) * HWPIX + p0 + threadIdx.x];
  __syncthreads();
#pragma unroll
  for (int i = 0; i < 4; i++)
    xTb[(size_t)(p0 + threadIdx.y + i * 8) * CIN + c0 + threadIdx.x] =
        tile[threadIdx.x][threadIdx.y + i * 8];
}

__global__ __launch_bounds__(256) void transpose_wd_kernel(const float* __restrict__ wd,
                                                           float* __restrict__ wdT) {
  int t = blockIdx.x * 256 + threadIdx.x;
  if (t >= 9 * 64 * 64) return;
  int cout = t & 63;
  int cin  = (t >> 6) & 63;
  int kk   = t >> 12;
  wdT[t] = wd[cout * 576 + cin * 9 + kk];
}

// 2 vertical pixels per thread; weights staged in LDS rows of 20 floats
// (18 used), read as 4x float4 + 1x float2 per tap -> 5 LDS instrs / 36 FMA.
__global__ __launch_bounds__(128) void offset_conv_kernel(const float* __restrict__ x,
                                                          const float* __restrict__ wo,
                                                          float* __restrict__ offs) {
  __shared__ float wl[576][20];   // [cin*9+ki*3+kj][c18], pitch 80B (16B-aligned rows)
  int tid = threadIdx.x;          // = x column, 0..127
  for (int i = tid; i < 18 * 576; i += 128) {
    int c = i % 18;
    int j = i / 18;
    wl[j][c] = wo[c * 576 + j];
  }
  __syncthreads();

  int bid = blockIdx.x;           // 256 blocks: 4 b * 64 row-pairs
  int b   = bid >> 6;
  int y0  = (bid & 63) << 1;      // rows y0, y0+1
  int xx  = tid;
  const float* xb = x + (size_t)b * CIN * HWPIX;

  float a0[18], a1[18];
#pragma unroll
  for (int c = 0; c < 18; c++) { a0[c] = 0.f; a1[c] = 0.f; }

  for (int cin = 0; cin < CIN; cin++) {
    const float* xc = xb + (size_t)cin * HWPIX;
    float xv[4][3];
#pragma unroll
    for (int r = 0; r < 4; r++) {
      int yy = y0 - 1 + r;
      bool vy = (yy >= 0) && (yy < HH);
      const float* xr = xc + yy * WW;
      xv[r][0] = (vy && xx > 0)      ? xr[xx - 1] : 0.f;
      xv[r][1] = vy                  ? xr[xx]     : 0.f;
      xv[r][2] = (vy && xx < WW - 1) ? xr[xx + 1] : 0.f;
    }
#pragma unroll
    for (int ki = 0; ki < 3; ki++) {
#pragma unroll
      for (int kj = 0; kj < 3; kj++) {
        const float* wr = &wl[cin * 9 + ki * 3 + kj][0];
        float4 w0 = *(const float4*)(wr + 0);
        float4 w1 = *(const float4*)(wr + 4);
        float4 w2 = *(const float4*)(wr + 8);
        float4 w3 = *(const float4*)(wr + 12);
        float2 w4 = *(const float2*)(wr + 16);
        float s0 = xv[ki][kj];      // contributes to px (y0)
        float s1 = xv[ki + 1][kj];  // contributes to px (y0+1)
        a0[0]  += w0.x * s0; a0[1]  += w0.y * s0; a0[2]  += w0.z * s0; a0[3]  += w0.w * s0;
        a0[4]  += w1.x * s0; a0[5]  += w1.y * s0; a0[6]  += w1.z * s0; a0[7]  += w1.w * s0;
        a0[8]  += w2.x * s0; a0[9]  += w2.y * s0; a0[10] += w2.z * s0; a0[11] += w2.w * s0;
        a0[12] += w3.x * s0; a0[13] += w3.y * s0; a0[14] += w3.z * s0; a0[15] += w3.w * s0;
        a0[16] += w4.x * s0; a0[17] += w4.y * s0;
        a1[0]  += w0.x * s1; a1[1]  += w0.y * s1; a1[2]  += w0.z * s1; a1[3]  += w0.w * s1;
        a1[4]  += w1.x * s1; a1[5]  += w1.y * s1; a1[6]  += w1.z * s1; a1[7]  += w1.w * s1;
        a1[8]  += w2.x * s1; a1[9]  += w2.y * s1; a1[10] += w2.z * s1; a1[11] += w2.w * s1;
        a1[12] += w3.x * s1; a1[13] += w3.y * s1; a1[14] += w3.z * s1; a1[15] += w3.w * s1;
        a1[16] += w4.x * s1; a1[17] += w4.y * s1;
      }
    }
  }
  float* o0 = offs + (size_t)b * 18 * HWPIX + y0 * WW + xx;
#pragma unroll
  for (int c = 0; c < 18; c++) {
    o0[(size_t)c * HWPIX]      = a0[c];
    o0[(size_t)c * HWPIX + WW] = a1[c];
  }
}

__global__ __launch_bounds__(256) void deform_gemm_kernel(const float* __restrict__ xT,
                                                          const float* __restrict__ offs,
                                                          const float* __restrict__ wdT,
                                                          float* __restrict__ out) {
  __shared__ float samp[CIN][68];
  __shared__ float wdl[CIN][COUT];
  int tid = threadIdx.x;
  // XCD swizzle: dispatch round-robins hw bid % 8 across XCDs; give each XCD
  // a contiguous 128-block band (64 consecutive y rows -> 2.1MB L2 working set).
  int hw  = blockIdx.x;
  int bid = (hw & 7) * 128 + (hw >> 3);
  int b   = bid >> 8;
  int r   = bid & 255;
  int y   = r >> 1;
  int x0  = (r & 1) << 6;

  int p1 = tid >> 2;   // pixel 0..63 (phase 1)
  int si = tid & 3;    // cin sub-slot (phase 1)
  int ci = tid & 15;   // cout quad (phase 2)
  int pi = tid >> 4;   // px quad (phase 2)

  const float* xTb = xT + (size_t)b * HWPIX * CIN;
  const float* ob  = offs + (size_t)b * 18 * HWPIX;

  float acc[4][4];
#pragma unroll
  for (int i = 0; i < 4; i++)
#pragma unroll
    for (int j = 0; j < 4; j++) acc[i][j] = 0.f;

  int xp = x0 + p1;
  int pixoff = y * WW + xp;

  for (int kk = 0; kk < 9; kk++) {
    {
      const float4* src = (const float4*)(wdT + (size_t)kk * CIN * COUT);
      float4* dst = (float4*)&wdl[0][0];
#pragma unroll
      for (int i = 0; i < 4; i++) dst[tid + i * 256] = src[tid + i * 256];
    }
    {
      float dy = ob[(size_t)(2 * kk) * HWPIX + pixoff];
      float dx = ob[(size_t)(2 * kk + 1) * HWPIX + pixoff];
      float ys = (float)(y - 1 + kk / 3) + dy;
      float xs = (float)(xp - 1 + kk % 3) + dx;
      float y0f = floorf(ys), x0f = floorf(xs);
      float wy = ys - y0f, wx = xs - x0f;
      int iy0 = (int)y0f, ix0 = (int)x0f;
      int iy1 = iy0 + 1, ix1 = ix0 + 1;
      float w00 = (1.f - wy) * (1.f - wx), w01 = (1.f - wy) * wx;
      float w10 = wy * (1.f - wx), w11 = wy * wx;
      bool vy0 = (iy0 >= 0) && (iy0 < HH), vy1 = (iy1 >= 0) && (iy1 < HH);
      bool vx0 = (ix0 >= 0) && (ix0 < WW), vx1 = (ix1 >= 0) && (ix1 < WW);
      if (!(vy0 && vx0)) w00 = 0.f;
      if (!(vy0 && vx1)) w01 = 0.f;
      if (!(vy1 && vx0)) w10 = 0.f;
      if (!(vy1 && vx1)) w11 = 0.f;
      int cy0 = min(max(iy0, 0), HH - 1), cy1 = min(max(iy1, 0), HH - 1);
      int cx0 = min(max(ix0, 0), WW - 1), cx1 = min(max(ix1, 0), WW - 1);
      // cin = c4*16 + si*4 + j  (si in low bits -> samp-store banks split
      // by si parity = 2-way = free, instead of 4-way)
      const float* q00 = xTb + ((size_t)(cy0 * WW + cx0)) * CIN + si * 4;
      const float* q01 = xTb + ((size_t)(cy0 * WW + cx1)) * CIN + si * 4;
      const float* q10 = xTb + ((size_t)(cy1 * WW + cx0)) * CIN + si * 4;
      const float* q11 = xTb + ((size_t)(cy1 * WW + cx1)) * CIN + si * 4;
#pragma unroll
      for (int c4 = 0; c4 < 4; c4++) {
        float4 v00 = *(const float4*)(q00 + c4 * 16);
        float4 v01 = *(const float4*)(q01 + c4 * 16);
        float4 v10 = *(const float4*)(q10 + c4 * 16);
        float4 v11 = *(const float4*)(q11 + c4 * 16);
        int cin = c4 * 16 + si * 4;
        samp[cin + 0][p1] = w00 * v00.x + w01 * v01.x + w10 * v10.x + w11 * v11.x;
        samp[cin + 1][p1] = w00 * v00.y + w01 * v01.y + w10 * v10.y + w11 * v11.y;
        samp[cin + 2][p1] = w00 * v00.z + w01 * v01.z + w10 * v10.z + w11 * v11.z;
        samp[cin + 3][p1] = w00 * v00.w + w01 * v01.w + w10 * v10.w + w11 * v11.w;
      }
    }
    __syncthreads();
#pragma unroll 16
    for (int c = 0; c < CIN; c++) {
      float4 wv = *(const float4*)&wdl[c][ci * 4];
      float4 sv = *(const float4*)&samp[c][pi * 4];
      acc[0][0] += wv.x * sv.x; acc[0][1] += wv.x * sv.y; acc[0][2] += wv.x * sv.z; acc[0][3] += wv.x * sv.w;
      acc[1][0] += wv.y * sv.x; acc[1][1] += wv.y * sv.y; acc[1][2] += wv.y * sv.z; acc[1][3] += wv.y * sv.w;
      acc[2][0] += wv.z * sv.x; acc[2][1] += wv.z * sv.y; acc[2][2] += wv.z * sv.z; acc[2][3] += wv.z * sv.w;
      acc[3][0] += wv.w * sv.x; acc[3][1] += wv.w * sv.y; acc[3][2] += wv.w * sv.z; acc[3][3] += wv.w * sv.w;
    }
    __syncthreads();
  }

  float* outb = out + (size_t)b * COUT * HWPIX + y * WW + x0 + pi * 4;
#pragma unroll
  for (int i = 0; i < 4; i++) {
    float4 v = make_float4(acc[i][0], acc[i][1], acc[i][2], acc[i][3]);
    *(float4*)(outb + (size_t)(ci * 4 + i) * HWPIX) = v;
  }
}

extern "C" void kernel_launch(void* const* d_in, const int* in_sizes, int n_in,
                              void* d_out, int out_size, void* d_ws, size_t ws_size,
                              hipStream_t stream) {
  const float* x  = (const float*)d_in[0];
  const float* wo = (const float*)d_in[1];
  const float* wd = (const float*)d_in[2];
  float* out = (float*)d_out;

  float* xT   = (float*)d_ws;
  float* offs = xT + (size_t)BATCH * CIN * HWPIX;
  float* wdT  = offs + (size_t)BATCH * 18 * HWPIX;

  transpose_x_kernel<<<dim3(HWPIX / 32, CIN / 32, BATCH), dim3(32, 8, 1), 0, stream>>>(x, xT);
  transpose_wd_kernel<<<dim3((9 * 64 * 64 + 255) / 256), dim3(256), 0, stream>>>(wd, wdT);
  offset_conv_kernel<<<dim3(BATCH * HH / 2), dim3(128), 0, stream>>>(x, wo, offs);
  deform_gemm_kernel<<<dim3(BATCH * HWPIX / 64), dim3(256), 0, stream>>>(xT, offs, wdT, out);
}